// Round 3
// baseline (352.487 us; speedup 1.0000x reference)
//
#include <hip/hip_runtime.h>

#define SEQ   1024
#define BATCH 512
#define NC    48
#define CH    8

typedef float f4 __attribute__((ext_vector_type(4)));

__device__ __forceinline__ float rfl(float x) {
    return __int_as_float(__builtin_amdgcn_readfirstlane(__float_as_int(x)));
}

// v + row_ror:N(v) within each 16-lane row, via update_dpp feeding a plain add.
// GCNDPPCombine fuses this into v_add_f32_dpp; compiler handles all hazards.
// row_ror:N ctrl encoding = 0x120 | N.
#define DPP_RADD(v, ctrl) \
    ((v) + __int_as_float(__builtin_amdgcn_update_dpp( \
        0, __float_as_int(v), (ctrl), 0xf, 0xf, true)))

// all-reduce of v across lane pairs {l, l^16} / {l, l^32}.
// permlane16_swap swaps odd 16-rows of op0 with even 16-rows of op1; feeding
// v in both operands makes sum(out0,out1) == v[l] + v[l^16] on every lane.
__device__ __forceinline__ float xadd16(float v) {
#if __has_builtin(__builtin_amdgcn_permlane16_swap)
    auto r = __builtin_amdgcn_permlane16_swap(__float_as_uint(v), __float_as_uint(v), false, false);
    return __uint_as_float(r[0]) + __uint_as_float(r[1]);
#else
    return v + __shfl_xor(v, 16, 64);
#endif
}
__device__ __forceinline__ float xadd32(float v) {
#if __has_builtin(__builtin_amdgcn_permlane32_swap)
    auto r = __builtin_amdgcn_permlane32_swap(__float_as_uint(v), __float_as_uint(v), false, false);
    return __uint_as_float(r[0]) + __uint_as_float(r[1]);
#else
    return v + __shfl_xor(v, 32, 64);
#endif
}

// R8 = R7 algorithm, intrinsics-only cross-lane (no raw asm on critical path).
// Lanes form a 4x16 grid: p=lane>>4 (4 groups of 12 states), q=lane&15
// (16 groups of 3 states). Steps alternate orientation:
//   T_A: state S3 (z[3q..3q+2] per lane, replicated over p) -> S12: lane
//        computes its 12 outputs over its 3 inputs (36 FMA), then all-reduce
//        across the 16-lane row (4 rounds of fused DPP add, row_ror 8/4/2/1).
//   T_B: S12 -> S3: 12 inputs -> 3 outputs (36 FMA), reduce across p via
//        permlane16_swap + permlane32_swap (pure VALU).
// After each reduce the state is exactly replicated where the next step needs
// it -> no readlane chain, no LDS roundtrip on the critical path.
// Emissions exp(s_t) are produced once per column (coalesced loads, 1 exp per
// lane per t) into a 3KB double-buffered LDS chunk; each step's slice is
// prefetched into registers one step ahead (off critical path).
// Exact pow2 rescale (logZ-invariant) every 2 steps; unguarded main chunks.
__global__ __launch_bounds__(64, 1) void crf_fwd(
    const float* __restrict__ scores,   // [SEQ][BATCH][NC]
    const int*   __restrict__ target,   // [SEQ][BATCH]
    const int*   __restrict__ lengths,  // [BATCH]
    const float* __restrict__ trans,    // [NC][NC]
    float* __restrict__ out)            // [2*BATCH]: X, then X - logZ
{
    const int b    = blockIdx.x;
    const int lane = threadIdx.x;
    const int q    = lane & 15;
    const int p    = lane >> 4;
    const int jc   = (lane < NC) ? lane : (NC - 1);
    const int L    = lengths[b];                       // uniform within block
    const float LOG2E = 1.4426950408889634f;
    const float LN2   = 0.6931471805599453f;
    const size_t TS = (size_t)BATCH * NC;
    const float* sp = scores + (size_t)b * NC + jc;

    __shared__ __align__(16) float esmb[2][CH][NC];    // exp(s_t) staging

    // ---- raw score chunk staging (coalesced: lane jc owns column jc) ----
    float rA[CH], rB[CH];
    #define PREFETCH_RAW(buf, tbase) do { \
        _Pragma("unroll") \
        for (int j_ = 0; j_ < CH; ++j_) { \
            int tt_ = (tbase) + j_; if (tt_ > SEQ - 1) tt_ = SEQ - 1; \
            (buf)[j_] = sp[(size_t)tt_ * TS]; \
        } } while (0)
    PREFETCH_RAW(rA, 0);
    PREFETCH_RAW(rB, CH);

    // ---- target path score X (parallel over t, then reduce) ----
    float x = 0.f;
    #pragma unroll 4
    for (int t = lane; t < L; t += 64) {
        int cur = target[t * BATCH + b];
        float e = scores[(size_t)t * TS + (size_t)b * NC + cur];
        float tr = 0.f;
        if (t > 0) {
            int prev = target[(t - 1) * BATCH + b];
            tr = trans[prev * NC + cur];
        }
        x += e + tr;
    }
    #pragma unroll
    for (int k = 32; k >= 1; k >>= 1) x += __shfl_xor(x, k, 64);

    // ---- E tiles: EA[m][n] = exp(T[3q+m][12p+n]); EB[n][m] = exp(T[12p+n][3q+m])
    float EA[3][12], EB[12][3];
    #pragma unroll
    for (int m = 0; m < 3; ++m)
        #pragma unroll
        for (int n = 0; n < 12; ++n) {
            EA[m][n] = __builtin_amdgcn_exp2f(trans[(3*q+m)*NC + 12*p+n] * LOG2E);
            asm("" : "+v"(EA[m][n]));
        }
    #pragma unroll
    for (int n = 0; n < 12; ++n)
        #pragma unroll
        for (int m = 0; m < 3; ++m) {
            EB[n][m] = __builtin_amdgcn_exp2f(trans[(12*p+n)*NC + 3*q+m] * LOG2E);
            asm("" : "+v"(EB[n][m]));
        }

    // ---- t = 0 init: state S3, z[3q+m] = exp(s0[3q+m] - s0[0]) ----
    const float* s0p = scores + (size_t)b * NC;
    float i0 = s0p[3*q+0], i1 = s0p[3*q+1], i2 = s0p[3*q+2];
    float s00 = rfl(i0);                               // lane 0 holds s0[0]
    float z0_ = __builtin_amdgcn_exp2f((i0 - s00) * LOG2E);
    float z1_ = __builtin_amdgcn_exp2f((i1 - s00) * LOG2E);
    float z2_ = __builtin_amdgcn_exp2f((i2 - s00) * LOG2E);
    float S   = s00 * LOG2E;
    float y[12];

    // ---- esm production: one exp per lane per t, ds_write to chunk slot ----
    #define PRODUCE(slot, buf) do { if (lane < NC) { \
        _Pragma("unroll") \
        for (int j_ = 0; j_ < CH; ++j_) \
            esmb[slot][j_][lane] = __builtin_amdgcn_exp2f((buf)[j_] * LOG2E); \
        } } while (0)
    PRODUCE(0, rA);

    // esm register prefetch (1 step ahead)
    f4 eav0, eav1, eav2;       // T_A: esm[12p..12p+11]
    float eb0, eb1, eb2;       // T_B: esm[3q..3q+2]
    #define LOAD_EA(t_) do { \
        const f4* pe_ = (const f4*)(&esmb[((t_) >> 3) & 1][(t_) & 7][0]); \
        eav0 = pe_[3*p+0]; eav1 = pe_[3*p+1]; eav2 = pe_[3*p+2]; } while (0)
    #define LOAD_EB(t_) do { \
        const float* pb_ = &esmb[((t_) >> 3) & 1][(t_) & 7][0]; \
        eb0 = pb_[3*q+0]; eb1 = pb_[3*q+1]; eb2 = pb_[3*q+2]; } while (0)

    // 16-lane row all-reduce of w[0..11]: 4 rounds of fused DPP adds
    #define RROUND(ctrl) do { _Pragma("unroll") \
        for (int n_ = 0; n_ < 12; ++n_) w[n_] = DPP_RADD(w[n_], ctrl); } while (0)

    // exact pow2 rescale (logZ-invariant): every 2 steps
    #define RS3() do { \
        int ex_ = (__builtin_amdgcn_readfirstlane(__float_as_int(z0_)) >> 23) & 255; \
        float sc_ = __int_as_float((254 - ex_) << 23); \
        z0_ *= sc_; z1_ *= sc_; z2_ *= sc_; S += (float)(ex_ - 127); \
    } while (0)

    // T_A: S3 -> S12
    #define TA(LOADNEXT) do { \
        float w[12]; \
        _Pragma("unroll") \
        for (int n_ = 0; n_ < 12; ++n_) \
            w[n_] = fmaf(z2_, EA[2][n_], fmaf(z1_, EA[1][n_], z0_ * EA[0][n_])); \
        LOADNEXT; \
        RROUND(0x128); RROUND(0x124); RROUND(0x122); RROUND(0x121); \
        y[0] = w[0]*eav0.x; y[1]  = w[1]*eav0.y;  y[2]  = w[2]*eav0.z;  y[3]  = w[3]*eav0.w; \
        y[4] = w[4]*eav1.x; y[5]  = w[5]*eav1.y;  y[6]  = w[6]*eav1.z;  y[7]  = w[7]*eav1.w; \
        y[8] = w[8]*eav2.x; y[9]  = w[9]*eav2.y;  y[10] = w[10]*eav2.z; y[11] = w[11]*eav2.w; \
    } while (0)

    // T_B: S12 -> S3
    #define TB(LOADNEXT) do { \
        float a0 = y[0]*EB[0][0], a1 = y[0]*EB[0][1], a2 = y[0]*EB[0][2]; \
        float c0 = y[6]*EB[6][0], c1 = y[6]*EB[6][1], c2 = y[6]*EB[6][2]; \
        _Pragma("unroll") \
        for (int n_ = 1; n_ < 6; ++n_) { \
            a0 = fmaf(y[n_], EB[n_][0], a0); \
            a1 = fmaf(y[n_], EB[n_][1], a1); \
            a2 = fmaf(y[n_], EB[n_][2], a2); } \
        _Pragma("unroll") \
        for (int n_ = 7; n_ < 12; ++n_) { \
            c0 = fmaf(y[n_], EB[n_][0], c0); \
            c1 = fmaf(y[n_], EB[n_][1], c1); \
            c2 = fmaf(y[n_], EB[n_][2], c2); } \
        LOADNEXT; \
        float r0 = a0 + c0, r1 = a1 + c1, r2 = a2 + c2; \
        r0 = xadd16(r0); r1 = xadd16(r1); r2 = xadd16(r2); \
        r0 = xadd32(r0); r1 = xadd32(r1); r2 = xadd32(r2); \
        z0_ = r0 * eb0; z1_ = r1 * eb1; z2_ = r2 * eb2; \
        RS3(); \
    } while (0)

    // ---- main loop: unguarded 8-step super-iterations (steps t0+1..t0+8) ----
    LOAD_EA(1);
    int t0 = 0;
    while (t0 + 9 <= L) {
        int kp = (t0 >> 3) & 1;
        if (kp == 0) { PRODUCE(1, rB); PREFETCH_RAW(rA, t0 + 2*CH); }
        else         { PRODUCE(0, rA); PREFETCH_RAW(rB, t0 + 2*CH); }
        TA(LOAD_EB(t0+2)); TB(LOAD_EA(t0+3));
        TA(LOAD_EB(t0+4)); TB(LOAD_EA(t0+5));
        TA(LOAD_EB(t0+6)); TB(LOAD_EA(t0+7));
        TA(LOAD_EB(t0+8)); TB(LOAD_EA(t0+9));
        t0 += CH;
    }

    // ---- tail: steps t0+1 .. L-1 (esm all within the produced chunk) ----
    int t = t0 + 1;
    int lastA = 0;
    while (t + 1 <= L - 1) {
        TA(LOAD_EB(t+1)); TB(LOAD_EA(t+2));
        t += 2;
    }
    if (t <= L - 1) { TA((void)0); lastA = 1; }

    #undef TA
    #undef TB
    #undef RROUND
    #undef RS3
    #undef LOAD_EA
    #undef LOAD_EB
    #undef PRODUCE
    #undef PREFETCH_RAW

    // ---- finalize: Z = sum_j z[j]; logZ = ln2 * (log2(Z) + S) ----
    float Z;
    if (lastA) {
        // S12: lane holds z[12p..12p+11] (replicated over q) -> reduce over p
        float s = ((y[0]+y[1]) + (y[2]+y[3])) + ((y[4]+y[5]) + (y[6]+y[7]))
                + ((y[8]+y[9]) + (y[10]+y[11]));
        s += __shfl_xor(s, 16, 64);
        s += __shfl_xor(s, 32, 64);
        Z = s;
    } else {
        // S3: lane holds z[3q..3q+2] (replicated over p) -> reduce over q
        float s = z0_ + z1_ + z2_;
        s += __shfl_xor(s, 1, 64);
        s += __shfl_xor(s, 2, 64);
        s += __shfl_xor(s, 4, 64);
        s += __shfl_xor(s, 8, 64);
        Z = s;
    }
    float logZ = (__builtin_amdgcn_logf(Z) + S) * LN2;

    if (lane == 0) {
        out[b]         = x;          // output 0: X
        out[BATCH + b] = x - logZ;   // output 1: X - logZ
    }
}

extern "C" void kernel_launch(void* const* d_in, const int* in_sizes, int n_in,
                              void* d_out, int out_size, void* d_ws, size_t ws_size,
                              hipStream_t stream) {
    const float* scores  = (const float*)d_in[0];
    const int*   target  = (const int*)d_in[1];
    const int*   lengths = (const int*)d_in[2];
    const float* trans   = (const float*)d_in[3];
    float* out = (float*)d_out;
    crf_fwd<<<BATCH, 64, 0, stream>>>(scores, target, lengths, trans, out);
}

// Round 4
// 292.235 us; speedup vs baseline: 1.2062x; 1.2062x over previous
//
#include <hip/hip_runtime.h>

#define SEQ   1024
#define BATCH 512
#define NC    48
#define CH    8

typedef float f2 __attribute__((ext_vector_type(2)));
typedef float f4 __attribute__((ext_vector_type(4)));

__device__ __forceinline__ float rfl(float x) {
    return __int_as_float(__builtin_amdgcn_readfirstlane(__float_as_int(x)));
}
// packed fp32 FMA: acc.lo += a.lo*b.lo ; acc.hi += a.hi*b.hi  (proven in R6)
__device__ __forceinline__ void pkfma(f2& acc, f2 a, f2 b) {
    asm("v_pk_fma_f32 %0, %1, %2, %0" : "+v"(acc) : "v"(a), "v"(b));
}
#define LO2(Q) __builtin_shufflevector(Q, Q, 0, 1)
#define HI2(Q) __builtin_shufflevector(Q, Q, 2, 3)

// R9: instruction-count minimization. Evidence from R5/R6/R8: three very
// different step structures all ran at ~6 cy/instruction (lone wave issue
// cadence); VALUBusy == 2cy/6cy exactly. So the only lever is fewer
// instructions per step. Step = 1 ds_write + 12 ds_read_b128 (48-value
// broadcast, cheapest instr-count mechanism) + 24 v_pk_fma_f32 (48 MACs)
// + 4 tree adds + 1 esm mul ~= 42 instr vs R6's ~85. esm stays in
// registers (EXP8 per chunk); exact pow2 rescale every 4 steps; guards
// only in prologue/tail; same-wave LDS pipe ordering makes the
// write->read broadcast barrier-free.
__global__ __launch_bounds__(64, 1) void crf_fwd(
    const float* __restrict__ scores,   // [SEQ][BATCH][NC]
    const int*   __restrict__ target,   // [SEQ][BATCH]
    const int*   __restrict__ lengths,  // [BATCH]
    const float* __restrict__ trans,    // [NC][NC]
    float* __restrict__ out)            // [2*BATCH]: X, then X - logZ
{
    const int b    = blockIdx.x;
    const int lane = threadIdx.x;
    const int jc   = (lane < NC) ? lane : (NC - 1);   // lanes 48-63 mirror col 47 (never read)
    const int L    = lengths[b];                       // uniform within block
    const float LOG2E = 1.4426950408889634f;
    const float LN2   = 0.6931471805599453f;
    const size_t TS = (size_t)BATCH * NC;
    const float* sp = scores + (size_t)b * NC + jc;

    __shared__ __align__(16) float zbuf[64];

    // ---- register staging buffers + first two chunks in flight ----
    float A[CH], B[CH];
    #define PREFETCH(buf, tbase) do { \
        _Pragma("unroll") \
        for (int k_ = 0; k_ < CH; ++k_) { \
            int tt_ = (tbase) + k_; if (tt_ > SEQ - 1) tt_ = SEQ - 1; \
            (buf)[k_] = sp[(size_t)tt_ * TS]; \
        } } while (0)
    PREFETCH(A, 0);
    PREFETCH(B, CH);

    // ---- target path score X (parallel over t, then reduce) ----
    float x = 0.f;
    #pragma unroll 4
    for (int t = lane; t < L; t += 64) {
        int cur = target[t * BATCH + b];
        float e = scores[(size_t)t * TS + (size_t)b * NC + cur];
        float tr = 0.f;
        if (t > 0) {
            int prev = target[(t - 1) * BATCH + b];
            tr = trans[prev * NC + cur];
        }
        x += e + tr;
    }
    #pragma unroll
    for (int k = 32; k >= 1; k >>= 1) x += __shfl_xor(x, k, 64);

    // ---- E column jc as 24 packed pairs: ep[j] = {e^T[2j][jc], e^T[2j+1][jc]} ----
    f2 ep[24];
    #pragma unroll
    for (int k = 0; k < 24; ++k) {
        ep[k].x = __builtin_amdgcn_exp2f(trans[(2*k)*NC + jc] * LOG2E);
        ep[k].y = __builtin_amdgcn_exp2f(trans[(2*k+1)*NC + jc] * LOG2E);
        asm("" : "+v"(ep[k]));   // pin: no remat, stays in VGPRs
    }

    // ---- t = 0 init (uses raw A[0], before EXP8 converts the chunk) ----
    float sv_init = A[0];
    float s00 = rfl(sv_init);
    float z = __builtin_amdgcn_exp2f((sv_init - s00) * LOG2E);
    float S = s00 * LOG2E;

    // convert a chunk of raw scores to esm = e^s (off the z-chain)
    #define EXP8(buf) do { _Pragma("unroll") \
        for (int k_ = 0; k_ < CH; ++k_) (buf)[k_] = __builtin_amdgcn_exp2f((buf)[k_] * LOG2E); } while (0)
    EXP8(A);

    // exact pow2 rescale (logZ-invariant): every 4 steps
    #define RS() do { \
        int eb_ = (__builtin_amdgcn_readfirstlane(__float_as_int(z)) >> 23) & 255; \
        z *= __int_as_float((254 - eb_) << 23); \
        S += (float)(eb_ - 127); \
    } while (0)

    // one recurrence step: LDS all-broadcast + packed FMAs (min instr count)
    #define STEP_CORE(esmv, ZUPD) do { \
        zbuf[lane] = z; \
        asm volatile("" ::: "memory");  /* keep reads after the write */ \
        const f4* zq_ = (const f4*)zbuf; \
        f4 Q0=zq_[0], Q1=zq_[1], Q2=zq_[2],  Q3=zq_[3]; \
        f4 Q4=zq_[4], Q5=zq_[5], Q6=zq_[6],  Q7=zq_[7]; \
        f4 Q8=zq_[8], Q9=zq_[9], Q10=zq_[10], Q11=zq_[11]; \
        f2 k0 = LO2(Q0)*ep[0],  k1 = HI2(Q0)*ep[1]; \
        f2 k2 = LO2(Q1)*ep[2],  k3 = HI2(Q1)*ep[3]; \
        pkfma(k0, LO2(Q2),  ep[4]);   pkfma(k1, HI2(Q2),  ep[5]); \
        pkfma(k2, LO2(Q3),  ep[6]);   pkfma(k3, HI2(Q3),  ep[7]); \
        pkfma(k0, LO2(Q4),  ep[8]);   pkfma(k1, HI2(Q4),  ep[9]); \
        pkfma(k2, LO2(Q5),  ep[10]);  pkfma(k3, HI2(Q5),  ep[11]); \
        pkfma(k0, LO2(Q6),  ep[12]);  pkfma(k1, HI2(Q6),  ep[13]); \
        pkfma(k2, LO2(Q7),  ep[14]);  pkfma(k3, HI2(Q7),  ep[15]); \
        pkfma(k0, LO2(Q8),  ep[16]);  pkfma(k1, HI2(Q8),  ep[17]); \
        pkfma(k2, LO2(Q9),  ep[18]);  pkfma(k3, HI2(Q9),  ep[19]); \
        pkfma(k0, LO2(Q10), ep[20]);  pkfma(k1, HI2(Q10), ep[21]); \
        pkfma(k2, LO2(Q11), ep[22]);  pkfma(k3, HI2(Q11), ep[23]); \
        f2 kk = (k0 + k1) + (k2 + k3); \
        float znew_ = (kk.x + kk.y) * (esmv); \
        ZUPD; \
    } while (0)

    #define STEPU(buf, sidx)      STEP_CORE((buf)[sidx], z = znew_)
    #define STEPG(buf, sidx, tb)  STEP_CORE((buf)[sidx], if (((tb)+(sidx)) < L) z = znew_)

    #define CHUNK8U(buf) do { \
        STEPU(buf,0); STEPU(buf,1); STEPU(buf,2); STEPU(buf,3); RS(); \
        STEPU(buf,4); STEPU(buf,5); STEPU(buf,6); STEPU(buf,7); RS(); \
    } while (0)
    #define CHUNK8G(buf, tb) do { \
        STEPG(buf,0,tb); STEPG(buf,1,tb); STEPG(buf,2,tb); STEPG(buf,3,tb); RS(); \
        STEPG(buf,4,tb); STEPG(buf,5,tb); STEPG(buf,6,tb); STEPG(buf,7,tb); RS(); \
    } while (0)

    // prologue: steps 1..7 from chunk 0 (guarded; L may be small)
    STEPG(A,1,0); STEPG(A,2,0); STEPG(A,3,0); RS();
    STEPG(A,4,0); STEPG(A,5,0); STEPG(A,6,0); STEPG(A,7,0); RS();

    // main: unguarded full chunks [t0, t0+8); invariant: cur buffer holds
    // chunk t0 raw; the other buffer gets chunk t0+8 prefetched.
    int t0 = CH;
    int useB = 1;
    while (t0 + CH <= L) {
        if (useB) { PREFETCH(A, t0 + CH); EXP8(B); CHUNK8U(B); }
        else      { PREFETCH(B, t0 + CH); EXP8(A); CHUNK8U(A); }
        useB ^= 1;
        t0 += CH;
    }
    // guarded tail chunk (steps t0 .. L-1)
    if (t0 < L) {
        if (useB) { EXP8(B); CHUNK8G(B, t0); }
        else      { EXP8(A); CHUNK8G(A, t0); }
    }

    #undef STEP_CORE
    #undef STEPU
    #undef STEPG
    #undef CHUNK8U
    #undef CHUNK8G
    #undef RS
    #undef EXP8
    #undef PREFETCH

    // ---- finalize: logZ = ln2 * (log2(sum_j z_j) + S) ----
    float zs = (lane < NC) ? z : 0.f;
    #pragma unroll
    for (int k = 32; k >= 1; k >>= 1) zs += __shfl_xor(zs, k, 64);
    float logZ = (__builtin_amdgcn_logf(zs) + S) * LN2;

    if (lane == 0) {
        out[b]         = x;          // output 0: X
        out[BATCH + b] = x - logZ;   // output 1: X - logZ
    }
}

extern "C" void kernel_launch(void* const* d_in, const int* in_sizes, int n_in,
                              void* d_out, int out_size, void* d_ws, size_t ws_size,
                              hipStream_t stream) {
    const float* scores  = (const float*)d_in[0];
    const int*   target  = (const int*)d_in[1];
    const int*   lengths = (const int*)d_in[2];
    const float* trans   = (const float*)d_in[3];
    float* out = (float*)d_out;
    crf_fwd<<<BATCH, 64, 0, stream>>>(scores, target, lengths, trans, out);
}